// Round 7
// baseline (37.610 us; speedup 1.0000x reference)
//
#include <hip/hip_runtime.h>

#define Hd    256
#define OUTD  10
#define DDEP  12
#define TLEN  8192
#define NTHR  512
#define NBLK  256

// xs swizzle (breaks stride-4 lane pattern into 2-way-free)
__device__ __forceinline__ int ph(int j) { return j + (j >> 5); }
// W3s swizzle: row stride 264, col c -> c + (c>>5); chunk (o,cg) starts at
// 264*o + 33*cg -> bank (8o + cg + j) % 32, conflict-light scalar reads.
__device__ __forceinline__ int w3a(int o, int c) { return o * 264 + c + (c >> 5); }

// LDS float offsets
#define OFF_KS   512                      // Vs[2][256] before it
#define OFF_W3   (OFF_KS + DDEP * 12)     // Ks[12][12]
#define OFF_XS   (OFF_W3 + OUTD * 264)    // W3s[10][264]
#define XS_LOG   (2048 + DDEP)
#define XS_PHYS  (XS_LOG + (XS_LOG >> 5) + 4)
#define SMEM_FLOATS (OFF_XS + XS_PHYS)    // ~21.8 KB

__global__ __launch_bounds__(NTHR, 2) void fused_rnn_kernel(
    const float* __restrict__ x, const float* __restrict__ w1g,
    const float* __restrict__ W2, const float* __restrict__ W3,
    float* __restrict__ y)
{
    __shared__ float smem[SMEM_FLOATS];
    float* Vs  = smem;              // [2][256] ping-pong
    float* Ksm = smem + OFF_KS;     // [12][12]
    float* W3s = smem + OFF_W3;     // [10][264] swizzled
    float* xs  = smem + OFF_XS;

    const int tid = threadIdx.x;
    const int bid = blockIdx.x;
    const int b   = bid >> 2;
    const int t0  = (bid & 3) * 2048;
    const float* xb = x + b * TLEN;

    const int rg = tid >> 3;        // row group: rows 4rg..4rg+3
    const int cg = tid & 7;         // col group: cols 32cg..32cg+31

    // ---- W2 chunk into registers: 4 rows x 32 cols = 32 b128 loads ----
    const float4* W2v = (const float4*)W2;
    float4 W2r[4][8];
    #pragma unroll
    for (int i = 0; i < 4; ++i)
        #pragma unroll
        for (int k = 0; k < 8; ++k)
            W2r[i][k] = W2v[(4 * rg + i) * 64 + 8 * cg + k];

    // ---- stage xs (swizzled), W3s (swizzled), v0 = w1 ----
    for (int j = tid; j < XS_LOG; j += NTHR) {
        const int g = t0 - DDEP + j;
        xs[ph(j)] = (g >= 0) ? xb[g] : 0.0f;
    }
    for (int i = tid; i < OUTD * Hd; i += NTHR)
        W3s[w3a(i >> 8, i & 255)] = W3[i];
    if (tid < Hd) Vs[tid] = w1g[tid];
    __syncthreads();

    // ---- conv state ----
    const int ub = tid * 4;
    float acc[4][OUTD];
    #pragma unroll
    for (int i = 0; i < 4; ++i)
        #pragma unroll
        for (int o = 0; o < OUTD; ++o) acc[i][o] = 0.0f;
    float wn[4];
    #pragma unroll
    for (int i = 0; i < 4; ++i) wn[i] = xs[ph(ub + DDEP + i)];

    // ---- fused chain + K + conv loop ----
    #pragma unroll 1
    for (int d = 0; d < DDEP; ++d) {
        const float* vsrc = Vs + (d & 1) * Hd;
        float r0 = 0.f, r1 = 0.f, r2 = 0.f, r3 = 0.f;   // chain row partials
        float kp = 0.f;                                  // K partial (rg<10)

        #pragma unroll
        for (int hh = 0; hh < 2; ++hh) {
            float4 vb[4];
            #pragma unroll
            for (int k = 0; k < 4; ++k)
                vb[k] = ((const float4*)vsrc)[8 * cg + hh * 4 + k];
            #pragma unroll
            for (int k = 0; k < 4; ++k) {
                const float4 w0 = W2r[0][hh * 4 + k];
                const float4 w1r = W2r[1][hh * 4 + k];
                const float4 w2r = W2r[2][hh * 4 + k];
                const float4 w3r = W2r[3][hh * 4 + k];
                r0 = fmaf(w0.x, vb[k].x, r0);  r0 = fmaf(w0.y, vb[k].y, r0);
                r0 = fmaf(w0.z, vb[k].z, r0);  r0 = fmaf(w0.w, vb[k].w, r0);
                r1 = fmaf(w1r.x, vb[k].x, r1); r1 = fmaf(w1r.y, vb[k].y, r1);
                r1 = fmaf(w1r.z, vb[k].z, r1); r1 = fmaf(w1r.w, vb[k].w, r1);
                r2 = fmaf(w2r.x, vb[k].x, r2); r2 = fmaf(w2r.y, vb[k].y, r2);
                r2 = fmaf(w2r.z, vb[k].z, r2); r2 = fmaf(w2r.w, vb[k].w, r2);
                r3 = fmaf(w3r.x, vb[k].x, r3); r3 = fmaf(w3r.y, vb[k].y, r3);
                r3 = fmaf(w3r.z, vb[k].z, r3); r3 = fmaf(w3r.w, vb[k].w, r3);
            }
            if (rg < OUTD) {                  // K[d][rg] partial on same v chunk
                const float* w3p = W3s + 264 * rg + 33 * cg + hh * 16;
                #pragma unroll
                for (int k = 0; k < 4; ++k) {
                    kp = fmaf(w3p[4 * k + 0], vb[k].x, kp);
                    kp = fmaf(w3p[4 * k + 1], vb[k].y, kp);
                    kp = fmaf(w3p[4 * k + 2], vb[k].z, kp);
                    kp = fmaf(w3p[4 * k + 3], vb[k].w, kp);
                }
            }
        }

        // reduce chain partials over cg (8 lanes), write v_{d+1}
        if (d < DDEP - 1) {
            r0 += __shfl_xor(r0, 1); r0 += __shfl_xor(r0, 2); r0 += __shfl_xor(r0, 4);
            r1 += __shfl_xor(r1, 1); r1 += __shfl_xor(r1, 2); r1 += __shfl_xor(r1, 4);
            r2 += __shfl_xor(r2, 1); r2 += __shfl_xor(r2, 2); r2 += __shfl_xor(r2, 4);
            r3 += __shfl_xor(r3, 1); r3 += __shfl_xor(r3, 2); r3 += __shfl_xor(r3, 4);
            if (cg == 0)
                ((float4*)(Vs + ((d + 1) & 1) * Hd))[rg] =
                    make_float4(r0, r1, r2, r3);
        }
        // reduce K partial, write Ks[d][rg]
        if (rg < OUTD) {
            kp += __shfl_xor(kp, 1); kp += __shfl_xor(kp, 2); kp += __shfl_xor(kp, 4);
            if (cg == 0) Ksm[d * 12 + rg] = kp;
        }

        // conv step c = d-1 (fills the reduce/write/barrier stall)
        if (d > 0) {
            const float* kk = Ksm + (d - 1) * 12;
            const float4 kA = *(const float4*)kk;
            const float4 kB = *(const float4*)(kk + 4);
            const float2 kC = *(const float2*)(kk + 8);
            #pragma unroll
            for (int i = 0; i < 4; ++i) {
                const float xv = wn[i];
                acc[i][0] = fmaf(kA.x, xv, acc[i][0]);
                acc[i][1] = fmaf(kA.y, xv, acc[i][1]);
                acc[i][2] = fmaf(kA.z, xv, acc[i][2]);
                acc[i][3] = fmaf(kA.w, xv, acc[i][3]);
                acc[i][4] = fmaf(kB.x, xv, acc[i][4]);
                acc[i][5] = fmaf(kB.y, xv, acc[i][5]);
                acc[i][6] = fmaf(kB.z, xv, acc[i][6]);
                acc[i][7] = fmaf(kB.w, xv, acc[i][7]);
                acc[i][8] = fmaf(kC.x, xv, acc[i][8]);
                acc[i][9] = fmaf(kC.y, xv, acc[i][9]);
            }
            const float nw = xs[ph(ub + DDEP - d)];
            wn[3] = wn[2]; wn[2] = wn[1]; wn[1] = wn[0]; wn[0] = nw;
        }
        __syncthreads();
    }

    // ---- epilogue conv step c = DDEP-1 ----
    {
        const float* kk = Ksm + (DDEP - 1) * 12;
        const float4 kA = *(const float4*)kk;
        const float4 kB = *(const float4*)(kk + 4);
        const float2 kC = *(const float2*)(kk + 8);
        #pragma unroll
        for (int i = 0; i < 4; ++i) {
            const float xv = wn[i];
            acc[i][0] = fmaf(kA.x, xv, acc[i][0]);
            acc[i][1] = fmaf(kA.y, xv, acc[i][1]);
            acc[i][2] = fmaf(kA.z, xv, acc[i][2]);
            acc[i][3] = fmaf(kA.w, xv, acc[i][3]);
            acc[i][4] = fmaf(kB.x, xv, acc[i][4]);
            acc[i][5] = fmaf(kB.y, xv, acc[i][5]);
            acc[i][6] = fmaf(kB.z, xv, acc[i][6]);
            acc[i][7] = fmaf(kB.w, xv, acc[i][7]);
            acc[i][8] = fmaf(kC.x, xv, acc[i][8]);
            acc[i][9] = fmaf(kC.y, xv, acc[i][9]);
        }
    }

    // ---- write y: 40 consecutive floats per thread ----
    float buf[4 * OUTD];
    #pragma unroll
    for (int i = 0; i < 4; ++i)
        #pragma unroll
        for (int o = 0; o < OUTD; ++o) buf[i * OUTD + o] = acc[i][o];

    float* yb = y + (size_t)(b * TLEN + t0 + ub) * OUTD;
    #pragma unroll
    for (int v = 0; v < 10; ++v)
        *(float4*)(yb + v * 4) =
            make_float4(buf[4 * v], buf[4 * v + 1], buf[4 * v + 2], buf[4 * v + 3]);
}

extern "C" void kernel_launch(void* const* d_in, const int* in_sizes, int n_in,
                              void* d_out, int out_size, void* d_ws, size_t ws_size,
                              hipStream_t stream)
{
    const float* x  = (const float*)d_in[0];   // (64, 8192)
    const float* w1 = (const float*)d_in[1];   // (256, 1) contiguous
    const float* W2 = (const float*)d_in[2];   // (256, 256)
    const float* W3 = (const float*)d_in[3];   // (10, 256)
    float* y  = (float*)d_out;

    fused_rnn_kernel<<<NBLK, dim3(NTHR), 0, stream>>>(x, w1, W2, W3, y);
}

// Round 8
// 31.158 us; speedup vs baseline: 1.2071x; 1.2071x over previous
//
#include <hip/hip_runtime.h>

#define Hd    256
#define OUTD  10
#define DDEP  12
#define TLEN  8192

// xs swizzle: phys(j) = j + (j>>5)
__device__ __forceinline__ int ph(int j) { return j + (j >> 5); }

// ---------------- Kernel A: K builder (1 block, 512 threads) ----------------
// v_0 = w1; v_{d+1} = W2 * v_d; K[d][o] = W3[o] . v_d.  K -> Kb (12x12 padded).
__global__ __launch_bounds__(512, 1) void k_builder(
    const float* __restrict__ w1g, const float* __restrict__ W2,
    const float* __restrict__ W3, float* __restrict__ Kb)
{
    __shared__ float Vs[DDEP][Hd];
    __shared__ float W3s[OUTD * Hd];
    __shared__ float Ks[DDEP * 12];
    const int tid = threadIdx.x;
    const int rp = tid >> 2, q = tid & 3;       // rows {2rp,2rp+1}, col quarter q

    // W2 chunk into registers (column-chunk rotation (k+4q)&15 for bank spread)
    const float4* W2v = (const float4*)W2;
    float4 A0[16], A1[16];
    #pragma unroll
    for (int k = 0; k < 16; ++k) {
        const int m = (k + 4 * q) & 15;
        A0[k] = W2v[(2 * rp) * 64 + q * 16 + m];
        A1[k] = W2v[(2 * rp + 1) * 64 + q * 16 + m];
    }
    for (int i = tid; i < OUTD * Hd; i += 512) W3s[i] = W3[i];
    if (tid < Hd) Vs[0][tid] = w1g[tid];
    __syncthreads();

    // chain: v_{d+1} = W2 * v_d (history kept for batched K-dots)
    #pragma unroll 1
    for (int d = 0; d < DDEP - 1; ++d) {
        const float4* vsrc = (const float4*)Vs[d];
        float4 a0 = make_float4(0.f, 0.f, 0.f, 0.f);
        float4 a1 = make_float4(0.f, 0.f, 0.f, 0.f);
        #pragma unroll
        for (int k = 0; k < 16; ++k) {
            const float4 vv = vsrc[q * 16 + ((k + 4 * q) & 15)];
            a0.x = fmaf(A0[k].x, vv.x, a0.x);
            a0.y = fmaf(A0[k].y, vv.y, a0.y);
            a0.z = fmaf(A0[k].z, vv.z, a0.z);
            a0.w = fmaf(A0[k].w, vv.w, a0.w);
            a1.x = fmaf(A1[k].x, vv.x, a1.x);
            a1.y = fmaf(A1[k].y, vv.y, a1.y);
            a1.z = fmaf(A1[k].z, vv.z, a1.z);
            a1.w = fmaf(A1[k].w, vv.w, a1.w);
        }
        float p0 = (a0.x + a0.y) + (a0.z + a0.w);
        float p1 = (a1.x + a1.y) + (a1.z + a1.w);
        p0 += __shfl_xor(p0, 1);  p0 += __shfl_xor(p0, 2);
        p1 += __shfl_xor(p1, 1);  p1 += __shfl_xor(p1, 2);
        if (q == 0)
            ((float2*)Vs[d + 1])[rp] = make_float2(p0, p1);
        __syncthreads();
    }

    // batched K[d][o]: wave w handles d = w (and w+8 for w<4)
    {
        const int w = tid >> 6, l = tid & 63;
        #pragma unroll
        for (int dd = 0; dd < 2; ++dd) {
            const int d = w + dd * 8;
            if (d < DDEP) {
                const float4 vv = ((const float4*)Vs[d])[l];
                #pragma unroll
                for (int o = 0; o < OUTD; ++o) {
                    const float4 wv = ((const float4*)(W3s + o * Hd))[l];
                    float p = fmaf(wv.x, vv.x,
                              fmaf(wv.y, vv.y,
                              fmaf(wv.z, vv.z, wv.w * vv.w)));
                    p += __shfl_xor(p, 1);  p += __shfl_xor(p, 2);
                    p += __shfl_xor(p, 4);  p += __shfl_xor(p, 8);
                    p += __shfl_xor(p, 16); p += __shfl_xor(p, 32);
                    if (l == 0) Ks[d * 12 + o] = p;
                }
                if (l == 1) { Ks[d * 12 + 10] = 0.f; Ks[d * 12 + 11] = 0.f; }
            }
        }
    }
    __syncthreads();
    if (tid < DDEP * 12) Kb[tid] = Ks[tid];
}

// ---------------- Kernel B: causal FIR + coalesced writes -------------------
// y[b,t,o] = sum_{d<12} K[d][o] * x[b,t-d].  512 blocks (2/CU), 1024 pos each.
#define CB_THR 512
#define YB_N   (1024 * 11)                 // stride-11 LDS transpose buffer

__global__ __launch_bounds__(CB_THR, 2) void conv_kernel(
    const float* __restrict__ x, const float* __restrict__ Kb,
    float* __restrict__ y)
{
    __shared__ float yb[YB_N];             // 44 KB
    __shared__ float xs[1036 + (1036 >> 5) + 4];
    __shared__ float Ks[DDEP * 12];
    const int tid = threadIdx.x;
    const int b   = blockIdx.x >> 3;
    const int t0  = (blockIdx.x & 7) * 1024;
    const float* xb = x + b * TLEN;

    for (int j = tid; j < 1024 + DDEP; j += CB_THR) {
        const int g = t0 - DDEP + j;
        xs[ph(j)] = (g >= 0) ? xb[g] : 0.0f;
    }
    if (tid < DDEP * 12) Ks[tid] = Kb[tid];
    __syncthreads();

    const int ub = tid * 2;                // 2 consecutive positions per thread
    float acc0[OUTD], acc1[OUTD];
    #pragma unroll
    for (int o = 0; o < OUTD; ++o) { acc0[o] = 0.f; acc1[o] = 0.f; }

    float wn0 = xs[ph(ub + DDEP)];
    float wn1 = xs[ph(ub + DDEP + 1)];

    #pragma unroll
    for (int d = 0; d < DDEP; ++d) {
        const float4 kA = *(const float4*)&Ks[d * 12];
        const float4 kB = *(const float4*)&Ks[d * 12 + 4];
        const float2 kC = *(const float2*)&Ks[d * 12 + 8];
        acc0[0] = fmaf(kA.x, wn0, acc0[0]);  acc1[0] = fmaf(kA.x, wn1, acc1[0]);
        acc0[1] = fmaf(kA.y, wn0, acc0[1]);  acc1[1] = fmaf(kA.y, wn1, acc1[1]);
        acc0[2] = fmaf(kA.z, wn0, acc0[2]);  acc1[2] = fmaf(kA.z, wn1, acc1[2]);
        acc0[3] = fmaf(kA.w, wn0, acc0[3]);  acc1[3] = fmaf(kA.w, wn1, acc1[3]);
        acc0[4] = fmaf(kB.x, wn0, acc0[4]);  acc1[4] = fmaf(kB.x, wn1, acc1[4]);
        acc0[5] = fmaf(kB.y, wn0, acc0[5]);  acc1[5] = fmaf(kB.y, wn1, acc1[5]);
        acc0[6] = fmaf(kB.z, wn0, acc0[6]);  acc1[6] = fmaf(kB.z, wn1, acc1[6]);
        acc0[7] = fmaf(kB.w, wn0, acc0[7]);  acc1[7] = fmaf(kB.w, wn1, acc1[7]);
        acc0[8] = fmaf(kC.x, wn0, acc0[8]);  acc1[8] = fmaf(kC.x, wn1, acc1[8]);
        acc0[9] = fmaf(kC.y, wn0, acc0[9]);  acc1[9] = fmaf(kC.y, wn1, acc1[9]);
        wn1 = wn0;
        wn0 = xs[ph(ub + DDEP - 1 - d)];
    }

    // transpose via LDS: position p at stride 11 (gcd(22,32)=2 -> light conflicts)
    #pragma unroll
    for (int o = 0; o < OUTD; ++o) {
        yb[ub * 11 + o]      = acc0[o];
        yb[ub * 11 + 11 + o] = acc1[o];
    }
    __syncthreads();

    // coalesced y write: logical l -> LDS addr l + l/10; lane-contiguous float4
    float* yg = y + ((size_t)b * TLEN + t0) * OUTD;
    #pragma unroll
    for (int r = 0; r < 5; ++r) {
        const int l = (r * CB_THR + tid) * 4;
        float4 v;
        v.x = yb[l     + (l    ) / 10];
        v.y = yb[l + 1 + (l + 1) / 10];
        v.z = yb[l + 2 + (l + 2) / 10];
        v.w = yb[l + 3 + (l + 3) / 10];
        *(float4*)(yg + l) = v;
    }
}

extern "C" void kernel_launch(void* const* d_in, const int* in_sizes, int n_in,
                              void* d_out, int out_size, void* d_ws, size_t ws_size,
                              hipStream_t stream)
{
    const float* x  = (const float*)d_in[0];   // (64, 8192)
    const float* w1 = (const float*)d_in[1];   // (256, 1) contiguous
    const float* W2 = (const float*)d_in[2];   // (256, 256)
    const float* W3 = (const float*)d_in[3];   // (10, 256)
    float* y  = (float*)d_out;
    float* Kb = (float*)d_ws;                  // 144 floats

    k_builder<<<1, dim3(512), 0, stream>>>(w1, W2, W3, Kb);
    conv_kernel<<<512, dim3(CB_THR), 0, stream>>>(x, Kb, y);
}